// Round 6
// baseline (348.335 us; speedup 1.0000x reference)
//
#include <hip/hip_runtime.h>
#include <math.h>

// CRF mean-field, fully factorized (rank-28 Taylor of exp(g.g') x separable
// 3-D Gaussian convs), ONE persistent kernel with hand-rolled grid barriers.
// 116 blocks <= 256 CUs => co-resident. Barrier counter is monotonic
// (epoch-based); memset node zeroes it before each replay.
// Barrier lessons:
//   R4: agent-scope atomic LOAD poll = stale per-XCD L2, eviction-paced (~48us).
//   R5: atomicAdd(cnt,0) RMW poll = fresh but RMWs serialize at the coherence
//       point across 116 pollers (~23us/barrier).
//   R6: poll with sc0+sc1 (system-scope) plain LOAD via inline asm — bypasses
//       L1+L2, always fresh, concurrent reads pipeline. Arrive = one atomicAdd
//       per block. __threadfence release/acquire unchanged (proved correct).

constexpr int   NT    = 8192;
constexpr int   NB    = 116;                 // 112 bilateral + 4 spatial volumes
constexpr float SQL2E = 1.2011224087864498f; // sqrt(log2 e)
constexpr float LOG2E = 1.4426950408889634f;
constexpr float INVA  = 0.2f * SQL2E;        // spatial prescale

// W rows (NT floats): 0..27 M[ab] | 28 s1 | 29 s2 | 30..33 u1 | 34..37 u2
//                     38..153 cv  | 154 barrier counter
constexpr int R_M = 0, R_S1 = 28, R_S2 = 29, R_U1 = 30, R_U2 = 34, R_CV = 38;
constexpr int R_CNT = 154;

__constant__ float INVSQF[7] = {1.f, 1.f, 0.70710678f, 0.40824829f,
                                0.20412415f, 0.09128709f, 0.03726780f};

static __device__ __forceinline__ float ex2(float x) {
    return __builtin_amdgcn_exp2f(x);
}

// System-scope (sc0 sc1) load: bypasses L1 and per-XCD L2, reads the
// coherence point. Fresh on every poll; concurrent readers pipeline.
static __device__ __forceinline__ unsigned sysload(const unsigned* p) {
    unsigned v;
    asm volatile("global_load_dword %0, %1, off sc0 sc1\n\t"
                 "s_waitcnt vmcnt(0)"
                 : "=v"(v) : "v"(p) : "memory");
    return v;
}

static __device__ __forceinline__ void gridbar(unsigned* cnt, unsigned target) {
    __syncthreads();
    if (threadIdx.x == 0) {
        __threadfence();                       // release: writeback XCD L2
        atomicAdd(cnt, 1u);                    // arrive (memory-side RMW)
        while (sysload(cnt) < target)
            __builtin_amdgcn_s_sleep(2);       // ~128 cyc backoff
        __threadfence();                       // acquire: invalidate stale L2
    }
    __syncthreads();
}

// Separable 3-D Gaussian conv of the volume in SP (512x17-padded), in place,
// result written to global row outp. Layout n = x*256 + y*16 + z.
static __device__ __forceinline__ void conv3d(float* SP, const float* g32,
                                              float* __restrict__ outp, int tid) {
    // z-pass: rows (x,y) at stride 17
#pragma unroll
    for (int rr = 0; rr < 2; rr++) {
        int r = tid + rr * 256;
        float v[16], acc[16];
#pragma unroll
        for (int z = 0; z < 16; z++) { v[z] = SP[r*17 + z]; acc[z] = 0.f; }
#pragma unroll
        for (int zp = 0; zp < 16; zp++)
#pragma unroll
            for (int z = 0; z < 16; z++) {
                int d = (z > zp) ? (z - zp) : (zp - z);
                acc[z] = fmaf(g32[d], v[zp], acc[z]);
            }
#pragma unroll
        for (int z = 0; z < 16; z++) SP[r*17 + z] = acc[z];
    }
    __syncthreads();
    // y-pass: rows (x,z), stride 17 between y's
#pragma unroll
    for (int rr = 0; rr < 2; rr++) {
        int r = tid + rr * 256;
        int base = (r >> 4) * 272 + (r & 15);
        float v[16], acc[16];
#pragma unroll
        for (int y = 0; y < 16; y++) { v[y] = SP[base + y*17]; acc[y] = 0.f; }
#pragma unroll
        for (int yp = 0; yp < 16; yp++)
#pragma unroll
            for (int y = 0; y < 16; y++) {
                int d = (y > yp) ? (y - yp) : (yp - y);
                acc[y] = fmaf(g32[d], v[yp], acc[y]);
            }
#pragma unroll
        for (int y = 0; y < 16; y++) SP[base + y*17] = acc[y];
    }
    __syncthreads();
    // x-pass: rows (y,z), stride 272; write to global
    {
        int base = (tid >> 4) * 17 + (tid & 15);
        float v[32], acc[32];
#pragma unroll
        for (int xp = 0; xp < 32; xp++) { v[xp] = SP[base + xp*272]; acc[xp] = 0.f; }
#pragma unroll
        for (int xp = 0; xp < 32; xp++)
#pragma unroll
            for (int x = 0; x < 32; x++) {
                int d = (x > xp) ? (x - xp) : (xp - x);
                acc[x] = fmaf(g32[d], v[xp], acc[x]);
            }
#pragma unroll
        for (int x = 0; x < 32; x++) outp[x*256 + tid] = acc[x];
    }
}

__global__ __launch_bounds__(256) void k_mega(const float* __restrict__ lu,
        const float* __restrict__ feat, const float* __restrict__ compat,
        float* __restrict__ out, float* __restrict__ W) {
    __shared__ float SP[512 * 17];
    const int bid = blockIdx.x, tid = threadIdx.x;
    unsigned* cnt = (unsigned*)(W + (size_t)R_CNT * NT);
    unsigned bar = 0;
    float g32[32];
#pragma unroll
    for (int d = 0; d < 32; d++) { float t = d * INVA; g32[d] = ex2(-0.5f*t*t); }

    // -------- phase A: blocks 0..27 build M[ab] from feat, conv -> cv[ab]
    if (bid < 28) {
        int a = 0, b = 0;
        { int r = bid;
          for (int k = 0; k <= 6; k++) { if (r <= k) { a = k - r; b = r; break; } r -= k + 1; } }
        float cN = INVSQF[a] * INVSQF[b];
        for (int s = tid; s < NT; s += 256) {
            float g0 = feat[s] * 0.2f, g1 = feat[NT + s] * 0.2f;
            float eg = ex2(-0.5f * LOG2E * (g0*g0 + g1*g1));
            float pa = 1.f;
            for (int i = 0; i < a; i++) pa *= g0;
            float pb = 1.f;
            for (int i = 0; i < b; i++) pb *= g1;
            float val = eg * pa * pb * cN;
            W[(R_M + bid)*NT + s] = val;
            SP[(s >> 4)*17 + (s & 15)] = val;
        }
        __syncthreads();
        conv3d(SP, g32, W + (size_t)(R_CV + bid)*NT, tid);
    }
    bar += NB; gridbar(cnt, bar);

    // -------- init: scale1 (rank-28 contract), scale2 (closed form), q0, u
    {
        int n = bid * 256 + tid;
        if (n < NT) {
            float rs = 0.f;
#pragma unroll
            for (int ab = 0; ab < 28; ab++)
                rs = fmaf(W[(R_M+ab)*NT + n], W[(R_CV+ab)*NT + n], rs);
            float s1 = rsqrtf(rs);
            int x = n >> 8, y = (n >> 4) & 15, z = n & 15;
            float Sx = 0.f, Sy = 0.f, Sz = 0.f;
            for (int j = 0; j < 32; j++) { float d = (float)(x-j)*INVA; Sx += ex2(-0.5f*d*d); }
            for (int j = 0; j < 16; j++) { float d = (float)(y-j)*INVA; Sy += ex2(-0.5f*d*d); }
            for (int j = 0; j < 16; j++) { float d = (float)(z-j)*INVA; Sz += ex2(-0.5f*d*d); }
            float s2 = rsqrtf(Sx * Sy * Sz);
            W[R_S1*NT+n] = s1; W[R_S2*NT+n] = s2;
            float l0 = lu[n], l1 = lu[NT+n], l2 = lu[2*NT+n], l3 = lu[3*NT+n];
            float mx = fmaxf(fmaxf(l0,l1), fmaxf(l2,l3));
            float q0 = __expf(l0-mx), q1 = __expf(l1-mx), q2 = __expf(l2-mx), q3 = __expf(l3-mx);
            float inv = 1.f / (q0+q1+q2+q3);
            q0*=inv; q1*=inv; q2*=inv; q3*=inv;
            W[(R_U1+0)*NT+n]=q0*s1; W[(R_U1+1)*NT+n]=q1*s1; W[(R_U1+2)*NT+n]=q2*s1; W[(R_U1+3)*NT+n]=q3*s1;
            W[(R_U2+0)*NT+n]=q0*s2; W[(R_U2+1)*NT+n]=q1*s2; W[(R_U2+2)*NT+n]=q2*s2; W[(R_U2+3)*NT+n]=q3*s2;
        }
    }

    // -------- 5 mean-field iterations
    for (int it = 0; it < 5; it++) {
        bar += NB; gridbar(cnt, bar);      // u ready -> conv may read
        if (bid < 112) {
            const float* Mr = W + (size_t)(R_M  + (bid >> 2)) * NT;
            const float* ur = W + (size_t)(R_U1 + (bid & 3)) * NT;
            for (int s = tid; s < NT; s += 256)
                SP[(s >> 4)*17 + (s & 15)] = Mr[s] * ur[s];
        } else {
            const float* ur = W + (size_t)(R_U2 + (bid - 112)) * NT;
            for (int s = tid; s < NT; s += 256)
                SP[(s >> 4)*17 + (s & 15)] = ur[s];
        }
        __syncthreads();
        conv3d(SP, g32, W + (size_t)(R_CV + bid)*NT, tid);
        bar += NB; gridbar(cnt, bar);      // cv ready -> fuse may read

        int n = bid * 256 + tid;
        if (n < NT) {
            float s1 = W[R_S1*NT+n], s2 = W[R_S2*NT+n];
            float y1[4] = {0.f, 0.f, 0.f, 0.f};
#pragma unroll
            for (int ab = 0; ab < 28; ab++) {
                float m = W[(R_M+ab)*NT + n];
#pragma unroll
                for (int c = 0; c < 4; c++)
                    y1[c] = fmaf(m, W[(R_CV + ab*4 + c)*NT + n], y1[c]);
            }
            float comb[4], q[4];
#pragma unroll
            for (int c = 0; c < 4; c++)
                comb[c] = s1 * y1[c] + s2 * W[(R_CV + 112 + c)*NT + n];
#pragma unroll
            for (int o = 0; o < 4; o++) {
                float upd = 0.f;
#pragma unroll
                for (int c = 0; c < 4; c++) upd = fmaf(compat[o*4+c], comb[c], upd);
                q[o] = lu[o*NT+n] - upd;
            }
            float mx = fmaxf(fmaxf(q[0],q[1]), fmaxf(q[2],q[3]));
            float sum = 0.f;
#pragma unroll
            for (int c = 0; c < 4; c++) { q[c] = __expf(q[c]-mx); sum += q[c]; }
            float inv = 1.f / sum;
#pragma unroll
            for (int c = 0; c < 4; c++) {
                q[c] *= inv;
                if (it == 4) {
                    out[c*NT+n] = q[c];
                } else {
                    W[(R_U1+c)*NT+n] = q[c]*s1;
                    W[(R_U2+c)*NT+n] = q[c]*s2;
                }
            }
        }
    }
}

// ---------------------------------------------------------------- driver
extern "C" void kernel_launch(void* const* d_in, const int* in_sizes, int n_in,
                              void* d_out, int out_size, void* d_ws, size_t ws_size,
                              hipStream_t stream) {
    const float* lu     = (const float*)d_in[0];
    const float* feat   = (const float*)d_in[1];
    const float* compat = (const float*)d_in[2];
    float* out = (float*)d_out;
    float* W   = (float*)d_ws;          // uses 155 rows * 32 KB ~= 5.1 MB

    // zero the grid-barrier counter (memset node is graph-capture safe)
    hipMemsetAsync((char*)d_ws + (size_t)R_CNT * NT * sizeof(float), 0, 64, stream);
    k_mega<<<dim3(NB), dim3(256), 0, stream>>>(lu, feat, compat, out, W);
}

// Round 7
// 318.202 us; speedup vs baseline: 1.0947x; 1.0947x over previous
//
#include <hip/hip_runtime.h>
#include <math.h>

// CRF mean-field, fully factorized (rank-28 Taylor of exp(g.g') x separable
// 3-D Gaussian convs), ONE persistent kernel with hand-rolled grid barriers.
// Barrier history:
//   R4: agent-scope atomic LOAD poll -> stale per-XCD L2 (~48us/barrier).
//   R5: atomicAdd(cnt,0) RMW poll    -> ~23us/barrier.
//   R6: sc0sc1 bypass-load poll      -> identical ~23us/barrier => poll path
//       was not the bottleneck; the single barrier LINE is congested (116
//       pollers + 116 RMW arrivals serialized on one line's service queue).
//   R7: decongest. Arrivals spread over 32 lines (bid&31, 256B apart).
//       Dedicated root block sweeps counters with a 32-lane bypass load and
//       publishes a generation word replicated on 4 lines; waiters poll only
//       gen (read-only) with long backoff. Fence protocol unchanged (R4-R6
//       correctness-proven). Launch-boundary data (R3: ~5us/gap incl. cache
//       flush) proves fences are cheap — contention was the cost.

constexpr int   NT    = 8192;
constexpr int   NBC   = 116;                 // compute blocks (112 bilateral + 4 spatial)
constexpr int   NB    = NBC + 1;             // + root barrier-server block
constexpr float SQL2E = 1.2011224087864498f; // sqrt(log2 e)
constexpr float LOG2E = 1.4426950408889634f;
constexpr float INVA  = 0.2f * SQL2E;        // spatial prescale

// W rows (NT floats): 0..27 M[ab] | 28 s1 | 29 s2 | 30..33 u1 | 34..37 u2
//                     38..153 cv  | 154 barrier structures
// Row 154: floats [i*64], i<32  : arrival counters (256B apart)
//          floats [2048 + i*64], i<4 : generation copies
constexpr int R_M = 0, R_S1 = 28, R_S2 = 29, R_U1 = 30, R_U2 = 34, R_CV = 38;
constexpr int R_BAR = 154;

__constant__ float INVSQF[7] = {1.f, 1.f, 0.70710678f, 0.40824829f,
                                0.20412415f, 0.09128709f, 0.03726780f};

static __device__ __forceinline__ float ex2(float x) {
    return __builtin_amdgcn_exp2f(x);
}

// System-scope (sc0 sc1) accesses: bypass L1 + per-XCD L2, hit the coherence
// point directly. Fresh reads; single-writer stores race-free.
static __device__ __forceinline__ unsigned sysload(const unsigned* p) {
    unsigned v;
    asm volatile("global_load_dword %0, %1, off sc0 sc1\n\t"
                 "s_waitcnt vmcnt(0)"
                 : "=v"(v) : "v"(p) : "memory");
    return v;
}
static __device__ __forceinline__ void sysstore(unsigned* p, unsigned v) {
    asm volatile("global_store_dword %0, %1, off sc0 sc1\n\t"
                 "s_waitcnt vmcnt(0)"
                 :: "v"(p), "v"(v) : "memory");
}

// Arrive: publish block's writes, bump this block's counter shard.
static __device__ __forceinline__ void arrive(unsigned* cnt, int bid) {
    __syncthreads();                       // drain block's stores (vmcnt at barrier)
    if (threadIdx.x == 0) {
        __threadfence();                   // release: writeback XCD L2
        atomicAdd(&cnt[(bid & 31) * 64], 1u);
    }
}

// Wait until generation >= e, then acquire.
static __device__ __forceinline__ void waitgen(unsigned* gen, int bid, unsigned e) {
    __syncthreads();                       // protect LDS reuse across phases
    if (threadIdx.x == 0) {
        unsigned* g = &gen[(bid & 3) * 64];
        while (sysload(g) < e)
            __builtin_amdgcn_s_sleep(16);  // ~1024 cyc backoff, low line pressure
        __threadfence();                   // acquire: invalidate stale L1/L2
    }
    __syncthreads();
}

// Separable 3-D Gaussian conv of the volume in SP (512x17-padded), in place,
// result written to global row outp. Layout n = x*256 + y*16 + z.
static __device__ __forceinline__ void conv3d(float* SP, const float* g32,
                                              float* __restrict__ outp, int tid) {
#pragma unroll
    for (int rr = 0; rr < 2; rr++) {       // z-pass
        int r = tid + rr * 256;
        float v[16], acc[16];
#pragma unroll
        for (int z = 0; z < 16; z++) { v[z] = SP[r*17 + z]; acc[z] = 0.f; }
#pragma unroll
        for (int zp = 0; zp < 16; zp++)
#pragma unroll
            for (int z = 0; z < 16; z++) {
                int d = (z > zp) ? (z - zp) : (zp - z);
                acc[z] = fmaf(g32[d], v[zp], acc[z]);
            }
#pragma unroll
        for (int z = 0; z < 16; z++) SP[r*17 + z] = acc[z];
    }
    __syncthreads();
#pragma unroll
    for (int rr = 0; rr < 2; rr++) {       // y-pass
        int r = tid + rr * 256;
        int base = (r >> 4) * 272 + (r & 15);
        float v[16], acc[16];
#pragma unroll
        for (int y = 0; y < 16; y++) { v[y] = SP[base + y*17]; acc[y] = 0.f; }
#pragma unroll
        for (int yp = 0; yp < 16; yp++)
#pragma unroll
            for (int y = 0; y < 16; y++) {
                int d = (y > yp) ? (y - yp) : (yp - y);
                acc[y] = fmaf(g32[d], v[yp], acc[y]);
            }
#pragma unroll
        for (int y = 0; y < 16; y++) SP[base + y*17] = acc[y];
    }
    __syncthreads();
    {                                      // x-pass + global store
        int base = (tid >> 4) * 17 + (tid & 15);
        float v[32], acc[32];
#pragma unroll
        for (int xp = 0; xp < 32; xp++) { v[xp] = SP[base + xp*272]; acc[xp] = 0.f; }
#pragma unroll
        for (int xp = 0; xp < 32; xp++)
#pragma unroll
            for (int x = 0; x < 32; x++) {
                int d = (x > xp) ? (x - xp) : (xp - x);
                acc[x] = fmaf(g32[d], v[xp], acc[x]);
            }
#pragma unroll
        for (int x = 0; x < 32; x++) outp[x*256 + tid] = acc[x];
    }
}

__global__ __launch_bounds__(256) void k_mega(const float* __restrict__ lu,
        const float* __restrict__ feat, const float* __restrict__ compat,
        float* __restrict__ out, float* __restrict__ W) {
    __shared__ float SP[512 * 17];
    const int bid = blockIdx.x, tid = threadIdx.x;
    unsigned* cnt = (unsigned*)(W + (size_t)R_BAR * NT);
    unsigned* gen = cnt + 2048;

    // ---------------- root barrier-server block ----------------
    if (bid == NBC) {
        if (tid < 64) {
            const int lane = tid;
            const unsigned addper[11] = {28,32,116,32,116,32,116,32,116,32,116};
            unsigned exp = 0;
            for (int k = 0; k < 11; k++) {
                exp += addper[k];
                while (true) {
                    unsigned v = 0;
                    if (lane < 32) v = sysload(&cnt[lane * 64]);
#pragma unroll
                    for (int m = 16; m >= 1; m >>= 1) v += __shfl_xor(v, m, 64);
                    unsigned sum = __shfl(v, 0, 64);
                    if (sum >= exp) break;
                    __builtin_amdgcn_s_sleep(2);
                }
                if (lane < 4) sysstore(&gen[lane * 64], (unsigned)(k + 1));
            }
        }
        return;
    }

    float g32[32];
#pragma unroll
    for (int d = 0; d < 32; d++) { float t = d * INVA; g32[d] = ex2(-0.5f*t*t); }

    // -------- phase A: blocks 0..27 build M[ab] from feat, conv -> cv[ab]
    if (bid < 28) {
        int a = 0, b = 0;
        { int r = bid;
          for (int k = 0; k <= 6; k++) { if (r <= k) { a = k - r; b = r; break; } r -= k + 1; } }
        float cN = INVSQF[a] * INVSQF[b];
        for (int s = tid; s < NT; s += 256) {
            float g0 = feat[s] * 0.2f, g1 = feat[NT + s] * 0.2f;
            float eg = ex2(-0.5f * LOG2E * (g0*g0 + g1*g1));
            float pa = 1.f;
            for (int i = 0; i < a; i++) pa *= g0;
            float pb = 1.f;
            for (int i = 0; i < b; i++) pb *= g1;
            float val = eg * pa * pb * cN;
            W[(R_M + bid)*NT + s] = val;
            SP[(s >> 4)*17 + (s & 15)] = val;
        }
        __syncthreads();
        conv3d(SP, g32, W + (size_t)(R_CV + bid)*NT, tid);
        arrive(cnt, bid);                                   // bar1: 28 arrivals
    }

    // -------- init: blocks 0..31: scale1, scale2, q0, u1, u2
    if (bid < 32) {
        waitgen(gen, bid, 1);
        int n = bid * 256 + tid;
        float rs = 0.f;
#pragma unroll
        for (int ab = 0; ab < 28; ab++)
            rs = fmaf(W[(R_M+ab)*NT + n], W[(R_CV+ab)*NT + n], rs);
        float s1 = rsqrtf(rs);
        int x = n >> 8, y = (n >> 4) & 15, z = n & 15;
        float Sx = 0.f, Sy = 0.f, Sz = 0.f;
        for (int j = 0; j < 32; j++) { float d = (float)(x-j)*INVA; Sx += ex2(-0.5f*d*d); }
        for (int j = 0; j < 16; j++) { float d = (float)(y-j)*INVA; Sy += ex2(-0.5f*d*d); }
        for (int j = 0; j < 16; j++) { float d = (float)(z-j)*INVA; Sz += ex2(-0.5f*d*d); }
        float s2 = rsqrtf(Sx * Sy * Sz);
        W[R_S1*NT+n] = s1; W[R_S2*NT+n] = s2;
        float l0 = lu[n], l1 = lu[NT+n], l2 = lu[2*NT+n], l3 = lu[3*NT+n];
        float mx = fmaxf(fmaxf(l0,l1), fmaxf(l2,l3));
        float q0 = __expf(l0-mx), q1 = __expf(l1-mx), q2 = __expf(l2-mx), q3 = __expf(l3-mx);
        float inv = 1.f / (q0+q1+q2+q3);
        q0*=inv; q1*=inv; q2*=inv; q3*=inv;
        W[(R_U1+0)*NT+n]=q0*s1; W[(R_U1+1)*NT+n]=q1*s1; W[(R_U1+2)*NT+n]=q2*s1; W[(R_U1+3)*NT+n]=q3*s1;
        W[(R_U2+0)*NT+n]=q0*s2; W[(R_U2+1)*NT+n]=q1*s2; W[(R_U2+2)*NT+n]=q2*s2; W[(R_U2+3)*NT+n]=q3*s2;
        arrive(cnt, bid);                                   // bar2: 32 arrivals
    }

    // -------- 5 mean-field iterations
    for (int it = 0; it < 5; it++) {
        waitgen(gen, bid, 2 + 2*it);       // u ready
        if (bid < 112) {
            const float* Mr = W + (size_t)(R_M  + (bid >> 2)) * NT;
            const float* ur = W + (size_t)(R_U1 + (bid & 3)) * NT;
            for (int s = tid; s < NT; s += 256)
                SP[(s >> 4)*17 + (s & 15)] = Mr[s] * ur[s];
        } else {
            const float* ur = W + (size_t)(R_U2 + (bid - 112)) * NT;
            for (int s = tid; s < NT; s += 256)
                SP[(s >> 4)*17 + (s & 15)] = ur[s];
        }
        __syncthreads();
        conv3d(SP, g32, W + (size_t)(R_CV + bid)*NT, tid);
        arrive(cnt, bid);                                   // bar(3+2it): 116 arrivals

        if (bid < 32) {
            waitgen(gen, bid, 3 + 2*it);   // cv ready
            int n = bid * 256 + tid;
            float s1 = W[R_S1*NT+n], s2 = W[R_S2*NT+n];
            float y1[4] = {0.f, 0.f, 0.f, 0.f};
#pragma unroll
            for (int ab = 0; ab < 28; ab++) {
                float m = W[(R_M+ab)*NT + n];
#pragma unroll
                for (int c = 0; c < 4; c++)
                    y1[c] = fmaf(m, W[(R_CV + ab*4 + c)*NT + n], y1[c]);
            }
            float comb[4], q[4];
#pragma unroll
            for (int c = 0; c < 4; c++)
                comb[c] = s1 * y1[c] + s2 * W[(R_CV + 112 + c)*NT + n];
#pragma unroll
            for (int o = 0; o < 4; o++) {
                float upd = 0.f;
#pragma unroll
                for (int c = 0; c < 4; c++) upd = fmaf(compat[o*4+c], comb[c], upd);
                q[o] = lu[o*NT+n] - upd;
            }
            float mx = fmaxf(fmaxf(q[0],q[1]), fmaxf(q[2],q[3]));
            float sum = 0.f;
#pragma unroll
            for (int c = 0; c < 4; c++) { q[c] = __expf(q[c]-mx); sum += q[c]; }
            float inv = 1.f / sum;
#pragma unroll
            for (int c = 0; c < 4; c++) {
                q[c] *= inv;
                if (it == 4) {
                    out[c*NT+n] = q[c];
                } else {
                    W[(R_U1+c)*NT+n] = q[c]*s1;
                    W[(R_U2+c)*NT+n] = q[c]*s2;
                }
            }
            if (it < 4) arrive(cnt, bid);                   // bar(4+2it): 32 arrivals
        }
    }
}

// ---------------------------------------------------------------- driver
extern "C" void kernel_launch(void* const* d_in, const int* in_sizes, int n_in,
                              void* d_out, int out_size, void* d_ws, size_t ws_size,
                              hipStream_t stream) {
    const float* lu     = (const float*)d_in[0];
    const float* feat   = (const float*)d_in[1];
    const float* compat = (const float*)d_in[2];
    float* out = (float*)d_out;
    float* W   = (float*)d_ws;          // uses 155 rows * 32 KB ~= 5.1 MB

    // zero the barrier row (counters + gen copies); graph-capture safe
    hipMemsetAsync((char*)d_ws + (size_t)R_BAR * NT * sizeof(float), 0, 16384, stream);
    k_mega<<<dim3(NB), dim3(256), 0, stream>>>(lu, feat, compat, out, W);
}

// Round 8
// 247.334 us; speedup vs baseline: 1.4084x; 1.2865x over previous
//
#include <hip/hip_runtime.h>
#include <math.h>

// CRF mean-field, fully factorized (rank-28 Taylor of exp(g.g') x separable
// 3-D Gaussian convs), ONE persistent kernel with hand-rolled grid barriers.
// Barrier history:
//   R4: agent-scope atomic LOAD poll -> stale per-XCD L2 (~48us/barrier).
//   R5: RMW poll -> ~23us/barrier.  R6: sc0sc1 bypass-load poll -> same.
//   R7: sharded counters + root server -> ~21us/barrier. Mechanism-invariant
//       => the cost is the 232 __threadfence() calls per round: each emits
//       whole-L2 writeback/invalidate ops, ~14 blocks/XCD serialized.
//   R8: ZERO fences. All cross-block payload moves via system-scope relaxed
//       atomics (global_load/store sc0 sc1 = write-through coherence point,
//       always-fresh reads). Ordering: per-wave s_waitcnt vmcnt(0) before the
//       arrival atomic. M rows recomputed from cached read-only feat instead
//       of stored; s1/s2/lu live in fuse-block registers.

constexpr int   NT    = 8192;
constexpr int   NBC   = 116;                 // compute blocks
constexpr int   NB    = NBC + 1;             // + root barrier-server block
constexpr float SQL2E = 1.2011224087864498f;
constexpr float LOG2E = 1.4426950408889634f;
constexpr float INVA  = 0.2f * SQL2E;

// W rows (NT floats): 0..3 u1[c] | 4..7 u2[c] | 8..123 cv | 124 barrier row
// Barrier row: unsigned [i*64], i<32 arrival shards; [2048 + i*64], i<4 gen.
constexpr int R_U1 = 0, R_U2 = 4, R_CV = 8, R_BAR = 124;

__constant__ float INVSQF[7] = {1.f, 1.f, 0.70710678f, 0.40824829f,
                                0.20412415f, 0.09128709f, 0.03726780f};

static __device__ __forceinline__ float ex2(float x) {
    return __builtin_amdgcn_exp2f(x);
}

// System-scope relaxed accesses: sc0 sc1 — bypass L1 + per-XCD L2, served at
// the coherence point. Compiler schedules/pipelines them like normal vmem.
static __device__ __forceinline__ float sysldf(const float* p) {
    return __hip_atomic_load(p, __ATOMIC_RELAXED, __HIP_MEMORY_SCOPE_SYSTEM);
}
static __device__ __forceinline__ void sysstf(float* p, float v) {
    __hip_atomic_store(p, v, __ATOMIC_RELAXED, __HIP_MEMORY_SCOPE_SYSTEM);
}
static __device__ __forceinline__ unsigned sysldu(const unsigned* p) {
    return __hip_atomic_load(p, __ATOMIC_RELAXED, __HIP_MEMORY_SCOPE_SYSTEM);
}
static __device__ __forceinline__ void sysstu(unsigned* p, unsigned v) {
    __hip_atomic_store(p, v, __ATOMIC_RELAXED, __HIP_MEMORY_SCOPE_SYSTEM);
}

// Arrive: every wave drains its (bypass) stores to the coherence point, block
// barrier, then one counter bump. NO cache-maintenance fence.
static __device__ __forceinline__ void arrive(unsigned* cnt, int bid) {
    asm volatile("s_waitcnt vmcnt(0)" ::: "memory");
    __syncthreads();
    if (threadIdx.x == 0) atomicAdd(&cnt[(bid & 31) * 64], 1u);
}

// Wait for generation >= e. Payload reads after this are sc0sc1 (fresh), so
// no acquire cache-op needed.
static __device__ __forceinline__ void waitgen(unsigned* gen, int bid, unsigned e) {
    __syncthreads();
    if (threadIdx.x == 0) {
        const unsigned* g = &gen[(bid & 3) * 64];
        while (sysldu(g) < e) __builtin_amdgcn_s_sleep(8);
    }
    __syncthreads();
}

static __device__ __forceinline__ void decode_ab(int idx, int& a, int& b) {
    int r = idx;
    for (int k = 0; k <= 6; k++) { if (r <= k) { a = k - r; b = r; return; } r -= k + 1; }
    a = 0; b = 0;
}

// Separable 3-D Gaussian conv of SP (512x17-padded), result bypass-stored to
// global row outp. Layout n = x*256 + y*16 + z.
static __device__ __forceinline__ void conv3d(float* SP, const float* g32,
                                              float* __restrict__ outp, int tid) {
#pragma unroll
    for (int rr = 0; rr < 2; rr++) {       // z-pass
        int r = tid + rr * 256;
        float v[16], acc[16];
#pragma unroll
        for (int z = 0; z < 16; z++) { v[z] = SP[r*17 + z]; acc[z] = 0.f; }
#pragma unroll
        for (int zp = 0; zp < 16; zp++)
#pragma unroll
            for (int z = 0; z < 16; z++) {
                int d = (z > zp) ? (z - zp) : (zp - z);
                acc[z] = fmaf(g32[d], v[zp], acc[z]);
            }
#pragma unroll
        for (int z = 0; z < 16; z++) SP[r*17 + z] = acc[z];
    }
    __syncthreads();
#pragma unroll
    for (int rr = 0; rr < 2; rr++) {       // y-pass
        int r = tid + rr * 256;
        int base = (r >> 4) * 272 + (r & 15);
        float v[16], acc[16];
#pragma unroll
        for (int y = 0; y < 16; y++) { v[y] = SP[base + y*17]; acc[y] = 0.f; }
#pragma unroll
        for (int yp = 0; yp < 16; yp++)
#pragma unroll
            for (int y = 0; y < 16; y++) {
                int d = (y > yp) ? (y - yp) : (yp - y);
                acc[y] = fmaf(g32[d], v[yp], acc[y]);
            }
#pragma unroll
        for (int y = 0; y < 16; y++) SP[base + y*17] = acc[y];
    }
    __syncthreads();
    {                                      // x-pass + bypass store
        int base = (tid >> 4) * 17 + (tid & 15);
        float v[32], acc[32];
#pragma unroll
        for (int xp = 0; xp < 32; xp++) { v[xp] = SP[base + xp*272]; acc[xp] = 0.f; }
#pragma unroll
        for (int xp = 0; xp < 32; xp++)
#pragma unroll
            for (int x = 0; x < 32; x++) {
                int d = (x > xp) ? (x - xp) : (xp - x);
                acc[x] = fmaf(g32[d], v[xp], acc[x]);
            }
#pragma unroll
        for (int x = 0; x < 32; x++) sysstf(outp + x*256 + tid, acc[x]);
    }
}

__global__ __launch_bounds__(256) void k_mega(const float* __restrict__ lu,
        const float* __restrict__ feat, const float* __restrict__ compat,
        float* __restrict__ out, float* __restrict__ W) {
    __shared__ float SP[512 * 17];
    const int bid = blockIdx.x, tid = threadIdx.x;
    unsigned* cnt = (unsigned*)(W + (size_t)R_BAR * NT);
    unsigned* gen = cnt + 2048;
    float* Wcv = W + (size_t)R_CV * NT;

    // ---------------- root barrier-server block ----------------
    if (bid == NBC) {
        if (tid < 64) {
            const unsigned addper[11] = {28,32,116,32,116,32,116,32,116,32,116};
            unsigned exp = 0;
            for (int k = 0; k < 11; k++) {
                exp += addper[k];
                while (true) {
                    unsigned v = (tid < 32) ? sysldu(&cnt[tid * 64]) : 0u;
#pragma unroll
                    for (int m = 16; m >= 1; m >>= 1) v += __shfl_xor(v, m, 64);
                    if (__shfl(v, 0, 64) >= exp) break;
                    __builtin_amdgcn_s_sleep(2);
                }
                if (tid < 4) sysstu(&gen[tid * 64], (unsigned)(k + 1));
            }
        }
        return;
    }

    float g32[32];
#pragma unroll
    for (int d = 0; d < 32; d++) { float t = d * INVA; g32[d] = ex2(-0.5f*t*t); }

    int ca = 0, cb = 0;                    // conv-role Taylor exponents
    if (bid < 112) decode_ab(bid >> 2, ca, cb);
    const float ccN = INVSQF[ca] * INVSQF[cb];

    // -------- phase A: blocks 0..27 conv(M[ab]) -> cv[ab] (M from feat)
    if (bid < 28) {
        int a, b; decode_ab(bid, a, b);
        float cN = INVSQF[a] * INVSQF[b];
        for (int s = tid; s < NT; s += 256) {
            float g0 = feat[s] * 0.2f, g1 = feat[NT + s] * 0.2f;
            float eg = ex2(-0.5f * LOG2E * (g0*g0 + g1*g1));
            float pa = 1.f;
            for (int i = 0; i < a; i++) pa *= g0;
            float pb = 1.f;
            for (int i = 0; i < b; i++) pb *= g1;
            SP[(s >> 4)*17 + (s & 15)] = eg * pa * pb * cN;
        }
        __syncthreads();
        conv3d(SP, g32, Wcv + (size_t)bid * NT, tid);
        arrive(cnt, bid);                                   // bar1: 28
    }

    // -------- init (blocks 0..31): s1 (contract), s2 (closed form), q0, u
    float s1v = 0.f, s2v = 0.f, lv0=0.f, lv1=0.f, lv2=0.f, lv3=0.f;
    float p0[7], p1[7], egv = 0.f;
    if (bid < 32) {
        waitgen(gen, bid, 1);
        int n = bid * 256 + tid;
        float g0 = feat[n] * 0.2f, g1 = feat[NT + n] * 0.2f;
        egv = ex2(-0.5f * LOG2E * (g0*g0 + g1*g1));
        p0[0] = 1.f; p1[0] = 1.f;
#pragma unroll
        for (int i = 1; i < 7; i++) { p0[i] = p0[i-1]*g0; p1[i] = p1[i-1]*g1; }
        float rs = 0.f;
        int ab = 0;
#pragma unroll
        for (int k = 0; k <= 6; k++)
#pragma unroll
            for (int a = k; a >= 0; a--) {
                int b = k - a;
                float m = egv * p0[a]*INVSQF[a] * p1[b]*INVSQF[b];
                rs = fmaf(m, sysldf(&Wcv[(size_t)ab*NT + n]), rs);
                ab++;
            }
        s1v = rsqrtf(rs);
        int x = n >> 8, y = (n >> 4) & 15, z = n & 15;
        float Sx = 0.f, Sy = 0.f, Sz = 0.f;
        for (int j = 0; j < 32; j++) { float d = (float)(x-j)*INVA; Sx += ex2(-0.5f*d*d); }
        for (int j = 0; j < 16; j++) { float d = (float)(y-j)*INVA; Sy += ex2(-0.5f*d*d); }
        for (int j = 0; j < 16; j++) { float d = (float)(z-j)*INVA; Sz += ex2(-0.5f*d*d); }
        s2v = rsqrtf(Sx * Sy * Sz);
        lv0 = lu[n]; lv1 = lu[NT+n]; lv2 = lu[2*NT+n]; lv3 = lu[3*NT+n];
        float mx = fmaxf(fmaxf(lv0,lv1), fmaxf(lv2,lv3));
        float q0 = __expf(lv0-mx), q1 = __expf(lv1-mx), q2 = __expf(lv2-mx), q3 = __expf(lv3-mx);
        float inv = 1.f / (q0+q1+q2+q3);
        q0*=inv; q1*=inv; q2*=inv; q3*=inv;
        sysstf(&W[(size_t)(R_U1+0)*NT+n], q0*s1v); sysstf(&W[(size_t)(R_U1+1)*NT+n], q1*s1v);
        sysstf(&W[(size_t)(R_U1+2)*NT+n], q2*s1v); sysstf(&W[(size_t)(R_U1+3)*NT+n], q3*s1v);
        sysstf(&W[(size_t)(R_U2+0)*NT+n], q0*s2v); sysstf(&W[(size_t)(R_U2+1)*NT+n], q1*s2v);
        sysstf(&W[(size_t)(R_U2+2)*NT+n], q2*s2v); sysstf(&W[(size_t)(R_U2+3)*NT+n], q3*s2v);
        arrive(cnt, bid);                                   // bar2: 32
    }

    // -------- 5 mean-field iterations
    for (int it = 0; it < 5; it++) {
        waitgen(gen, bid, 2 + 2*it);       // u ready
        if (bid < 112) {
            const float* ur = W + (size_t)(R_U1 + (bid & 3)) * NT;
            for (int s = tid; s < NT; s += 256) {
                float g0 = feat[s] * 0.2f, g1 = feat[NT + s] * 0.2f;
                float eg = ex2(-0.5f * LOG2E * (g0*g0 + g1*g1));
                float pa = 1.f;
                for (int i = 0; i < ca; i++) pa *= g0;
                float pb = 1.f;
                for (int i = 0; i < cb; i++) pb *= g1;
                SP[(s >> 4)*17 + (s & 15)] = eg * pa * pb * ccN * sysldf(ur + s);
            }
        } else {
            const float* ur = W + (size_t)(R_U2 + (bid - 112)) * NT;
            for (int s = tid; s < NT; s += 256)
                SP[(s >> 4)*17 + (s & 15)] = sysldf(ur + s);
        }
        __syncthreads();
        conv3d(SP, g32, Wcv + (size_t)bid * NT, tid);
        arrive(cnt, bid);                                   // bar: 116

        if (bid < 32) {
            waitgen(gen, bid, 3 + 2*it);   // cv ready
            int n = bid * 256 + tid;
            float y1[4] = {0.f, 0.f, 0.f, 0.f};
            int ab = 0;
#pragma unroll
            for (int k = 0; k <= 6; k++)
#pragma unroll
                for (int a = k; a >= 0; a--) {
                    int b = k - a;
                    float m = egv * p0[a]*INVSQF[a] * p1[b]*INVSQF[b];
#pragma unroll
                    for (int c = 0; c < 4; c++)
                        y1[c] = fmaf(m, sysldf(&Wcv[(size_t)(ab*4 + c)*NT + n]), y1[c]);
                    ab++;
                }
            float comb[4], q[4];
#pragma unroll
            for (int c = 0; c < 4; c++)
                comb[c] = s1v * y1[c] + s2v * sysldf(&Wcv[(size_t)(112 + c)*NT + n]);
#pragma unroll
            for (int o = 0; o < 4; o++) {
                float upd = 0.f;
#pragma unroll
                for (int c = 0; c < 4; c++) upd = fmaf(compat[o*4+c], comb[c], upd);
                q[o] = ((o==0)?lv0:(o==1)?lv1:(o==2)?lv2:lv3) - upd;
            }
            float mx = fmaxf(fmaxf(q[0],q[1]), fmaxf(q[2],q[3]));
            float sum = 0.f;
#pragma unroll
            for (int c = 0; c < 4; c++) { q[c] = __expf(q[c]-mx); sum += q[c]; }
            float inv = 1.f / sum;
#pragma unroll
            for (int c = 0; c < 4; c++) {
                q[c] *= inv;
                if (it == 4) {
                    out[c*NT+n] = q[c];
                } else {
                    sysstf(&W[(size_t)(R_U1+c)*NT+n], q[c]*s1v);
                    sysstf(&W[(size_t)(R_U2+c)*NT+n], q[c]*s2v);
                }
            }
            if (it < 4) arrive(cnt, bid);                   // bar: 32
        }
    }
}

// ---------------------------------------------------------------- driver
extern "C" void kernel_launch(void* const* d_in, const int* in_sizes, int n_in,
                              void* d_out, int out_size, void* d_ws, size_t ws_size,
                              hipStream_t stream) {
    const float* lu     = (const float*)d_in[0];
    const float* feat   = (const float*)d_in[1];
    const float* compat = (const float*)d_in[2];
    float* out = (float*)d_out;
    float* W   = (float*)d_ws;          // 125 rows * 32 KB ~= 4.1 MB

    // zero the barrier row (counters + gen); graph-capture safe
    hipMemsetAsync((char*)d_ws + (size_t)R_BAR * NT * sizeof(float), 0, 16384, stream);
    k_mega<<<dim3(NB), dim3(256), 0, stream>>>(lu, feat, compat, out, W);
}